// Round 7
// baseline (95.856 us; speedup 1.0000x reference)
//
#include <hip/hip_runtime.h>

// Problem constants (from reference setup_inputs)
#define QDIM 900
#define CDIM 80
#define TDIM 300
#define QPB 36               // q's per block (4 waves x 9)
#define QPW 9                // q's per wave
#define NQB (QDIM / QPB)     // 25 blocks per batch

typedef float floatx4 __attribute__((ext_vector_type(4)));  // native vector for NT store

// Per-element cost from CORNERS-ONLY target state.
// cost = (2 - 2*sigmoid) + 5*L1 - 2*(inter/uni + uni/areac), with
//   cw = aw + bw - iwr   (enclosing-box identity)
//   L1x = 0.5*|dx0+dx1| + |dx1-dx0|   (corner identity for |dcx|+|dw|)
__device__ __forceinline__ float cost_one(
    float ax0, float ay0, float ax1, float ay1,
    float aw, float ah, float area_a,
    const float* __restrict__ cls_j,
    float bx0, float by0, float bx1, float by1, int lab)
{
    float clsv = cls_j[lab];

    // x axis
    float M0x = fmaxf(ax0, bx0);
    float m1x = fminf(ax1, bx1);
    float iwr = m1x - M0x;
    float iw  = fmaxf(iwr, 0.0f);
    float bw  = bx1 - bx0;
    float cw  = (aw + bw) - iwr;
    // y axis
    float M0y = fmaxf(ay0, by0);
    float m1y = fminf(ay1, by1);
    float ihr = m1y - M0y;
    float ih  = fmaxf(ihr, 0.0f);
    float bh  = by1 - by0;
    float ch  = (ah + bh) - ihr;

    float inter  = iw * ih;
    float areac  = cw * ch;
    float area_b = bw * bh;
    float uni    = (area_a + area_b) - inter;

    // inter/uni + uni/areac = (inter*areac + uni^2)/(uni*areac) -- one rcp
    float num   = fmaf(uni, uni, inter * areac);
    float den   = uni * areac;
    float ratio = num * __builtin_amdgcn_rcpf(den);

    // L1 via corner identities
    float dx0 = ax0 - bx0, dx1 = ax1 - bx1;
    float dy0 = ay0 - by0, dy1 = ay1 - by1;
    float l1x = fmaf(0.5f, fabsf(dx0 + dx1), fabsf(dx1 - dx0));
    float l1y = fmaf(0.5f, fabsf(dy0 + dy1), fabsf(dy1 - dy0));
    float l1  = l1x + l1y;

    float acc = fmaf(5.0f, l1, clsv);
    return fmaf(-2.0f, ratio, acc);
}

__global__ __launch_bounds__(256, 7) void matcher_cost_kernel(
    const float* __restrict__ pred_logits,  // [B,Q,C]
    const float* __restrict__ pred_boxes,   // [B,Q,4] cxcywh
    const int*   __restrict__ tgt_labels,   // [B,T]
    const float* __restrict__ tgt_boxes,    // [B,T,4] cxcywh
    float* __restrict__ out)                // [B,Q,T]
{
    // s_cls[ql*C + c] = 2 - 2*sigmoid(logit) = 2/(1+e^x)
    __shared__ float s_cls[QPB * CDIM];     // 11.25 KB

    const int tid = threadIdx.x;
    const int b  = blockIdx.x / NQB;
    const int q0 = (blockIdx.x % NQB) * QPB;

    const float* lg = pred_logits + ((size_t)b * QDIM + q0) * CDIM;
    for (int i = tid; i < QPB * CDIM; i += 256) {
        float x = lg[i];
        s_cls[i] = 2.0f * __builtin_amdgcn_rcpf(1.0f + __expf(x));
    }
    __syncthreads();

    const int wave = tid >> 6;
    const int lane = tid & 63;

    // ---- target CORNERS in registers (5 per lane: 4 vec-slice + 1 tail) ----
    // slice i<4: t = 4*lane + i   -> float4 NT store
    // slice 4  : t = 256 + lane   -> scalar NT store (lane < 44)
    float tx0[5], ty0[5], tx1[5], ty1[5];
    int   tlab[5];
    {
        const float4* tb4 = reinterpret_cast<const float4*>(tgt_boxes) + (size_t)b * TDIM;
        const int*    lb  = tgt_labels + (size_t)b * TDIM;
        #pragma unroll
        for (int k = 0; k < 5; ++k) {
            int t = (k < 4) ? (4 * lane + k) : (256 + lane);
            if (t > TDIM - 1) t = TDIM - 1;
            float4 v = tb4[t];
            float hw = 0.5f * v.z, hh = 0.5f * v.w;
            tx0[k] = v.x - hw; ty0[k] = v.y - hh;
            tx1[k] = v.x + hw; ty1[k] = v.y + hh;
            tlab[k] = lb[t];
        }
    }
    const bool bok = lane < (TDIM - 256);   // lane < 44

    // ---- q loop: wave owns 9 contiguous q's ----
    const int qw = q0 + wave * QPW;
    const float4* pb4 = reinterpret_cast<const float4*>(pred_boxes) + (size_t)b * QDIM + qw;
    float* orow0 = out + ((size_t)b * QDIM + qw) * TDIM;

    float4 a = pb4[0];
    #pragma unroll 1
    for (int j = 0; j < QPW; ++j) {
        float4 an = pb4[(j < QPW - 1) ? (j + 1) : j];   // prefetch next q box
        const float hw = 0.5f * a.z, hh = 0.5f * a.w;
        const float ax0 = a.x - hw, ay0 = a.y - hh;
        const float ax1 = a.x + hw, ay1 = a.y + hh;
        const float aw = a.z, ah = a.w;
        const float area_a = a.z * a.w;
        const float* cls_j = s_cls + (wave * QPW + j) * CDIM;
        float* po = orow0 + j * TDIM;

        floatx4 res;
        res.x = cost_one(ax0, ay0, ax1, ay1, aw, ah, area_a, cls_j,
                         tx0[0], ty0[0], tx1[0], ty1[0], tlab[0]);
        res.y = cost_one(ax0, ay0, ax1, ay1, aw, ah, area_a, cls_j,
                         tx0[1], ty0[1], tx1[1], ty1[1], tlab[1]);
        res.z = cost_one(ax0, ay0, ax1, ay1, aw, ah, area_a, cls_j,
                         tx0[2], ty0[2], tx1[2], ty1[2], tlab[2]);
        res.w = cost_one(ax0, ay0, ax1, ay1, aw, ah, area_a, cls_j,
                         tx0[3], ty0[3], tx1[3], ty1[3], tlab[3]);
        __builtin_nontemporal_store(res, reinterpret_cast<floatx4*>(po) + lane);

        float cB = cost_one(ax0, ay0, ax1, ay1, aw, ah, area_a, cls_j,
                            tx0[4], ty0[4], tx1[4], ty1[4], tlab[4]);
        if (bok)
            __builtin_nontemporal_store(cB, po + 256 + lane);

        a = an;
    }
}

extern "C" void kernel_launch(void* const* d_in, const int* in_sizes, int n_in,
                              void* d_out, int out_size, void* d_ws, size_t ws_size,
                              hipStream_t stream) {
    const float* pred_logits = (const float*)d_in[0];
    const float* pred_boxes  = (const float*)d_in[1];
    const int*   tgt_labels  = (const int*)d_in[2];
    const float* tgt_boxes   = (const float*)d_in[3];
    float* out = (float*)d_out;

    const int B = in_sizes[0] / (QDIM * CDIM);   // 256
    dim3 grid(B * NQB);                          // 256 * 25 = 6400
    dim3 block(256);
    matcher_cost_kernel<<<grid, block, 0, stream>>>(pred_logits, pred_boxes,
                                                    tgt_labels, tgt_boxes, out);
}

// Round 8
// 90.254 us; speedup vs baseline: 1.0621x; 1.0621x over previous
//
#include <hip/hip_runtime.h>

// Problem constants (from reference setup_inputs)
#define QDIM 900
#define CDIM 80
#define TDIM 300
#define QPB 36               // q's per block (4 waves x 9)
#define QPW 9                // q's per wave
#define NQB (QDIM / QPB)     // 25 blocks per batch

typedef float floatx2 __attribute__((ext_vector_type(2)));
typedef float floatx4 __attribute__((ext_vector_type(4)));

// Target state: x/y packed as float2 so axis math emits v_pk_*_f32 (VOP3P).
struct TgtReg {
    floatx2 p0;    // (x0, y0)
    floatx2 p1;    // (x1, y1)
    floatx2 wh;    // (w, h)
    floatx2 cc;    // (cx, cy)
    float   area;
    int     lab;
};

// cost = (2 - 2*sigmoid) + 5*L1 - 2*(inter/uni + uni/areac)
// enclosing box via identity cwh = (awh + bwh) - ir  (ir = unclamped overlap)
__device__ __forceinline__ float cost_one(
    floatx2 ap0, floatx2 ap1, floatx2 awh, floatx2 acc2, float area_a,
    const float* __restrict__ cls_j, const TgtReg& t)
{
    float clsv = cls_j[t.lab];

    floatx2 M0  = __builtin_elementwise_max(ap0, t.p0);   // v_pk_max_f32
    floatx2 m1  = __builtin_elementwise_min(ap1, t.p1);   // v_pk_min_f32
    floatx2 ir  = m1 - M0;                                // v_pk_add (neg)
    floatx2 iwh = __builtin_elementwise_max(ir, (floatx2)0.0f);
    floatx2 cwh = (awh + t.wh) - ir;                      // 2x v_pk

    float inter = iwh.x * iwh.y;
    float areac = cwh.x * cwh.y;
    float uni   = (area_a + t.area) - inter;

    // inter/uni + uni/areac = (inter*areac + uni^2)/(uni*areac) -- one rcp
    float num   = fmaf(uni, uni, inter * areac);
    float den   = uni * areac;
    float ratio = num * __builtin_amdgcn_rcpf(den);

    // L1 in cxcywh (packed diffs, abs folds into the adds as input mods)
    floatx2 dcc = acc2 - t.cc;
    floatx2 dwh = awh - t.wh;
    float l1 = (fabsf(dcc.x) + fabsf(dcc.y)) + (fabsf(dwh.x) + fabsf(dwh.y));

    float acc = fmaf(5.0f, l1, clsv);
    return fmaf(-2.0f, ratio, acc);
}

__device__ __forceinline__ TgtReg load_tgt(const float4* tb4, const int* lb, int t)
{
    TgtReg r;
    float4 v = tb4[t];
    float hw = 0.5f * v.z, hh = 0.5f * v.w;
    r.p0 = (floatx2){v.x - hw, v.y - hh};
    r.p1 = (floatx2){v.x + hw, v.y + hh};
    r.wh = (floatx2){v.z, v.w};
    r.cc = (floatx2){v.x, v.y};
    r.area = v.z * v.w;
    r.lab = lb[t];
    return r;
}

__global__ __launch_bounds__(256, 4) void matcher_cost_kernel(
    const float* __restrict__ pred_logits,  // [B,Q,C]
    const float* __restrict__ pred_boxes,   // [B,Q,4] cxcywh
    const int*   __restrict__ tgt_labels,   // [B,T]
    const float* __restrict__ tgt_boxes,    // [B,T,4] cxcywh
    float* __restrict__ out)                // [B,Q,T]
{
    // s_cls[ql*C + c] = 2 - 2*sigmoid(logit) = 2/(1+e^x)
    __shared__ float s_cls[QPB * CDIM];     // 11.25 KB

    const int tid = threadIdx.x;
    const int b  = blockIdx.x / NQB;
    const int q0 = (blockIdx.x % NQB) * QPB;

    const float* lg = pred_logits + ((size_t)b * QDIM + q0) * CDIM;
    for (int i = tid; i < QPB * CDIM; i += 256) {
        float x = lg[i];
        s_cls[i] = 2.0f * __builtin_amdgcn_rcpf(1.0f + __expf(x));
    }
    __syncthreads();

    const int wave = tid >> 6;
    const int lane = tid & 63;

    // ---- target data in registers ----
    // slice A: lane owns t = 4*lane .. 4*lane+3  (t < 256)  -> float4 NT store
    // slice B: lane owns t = 256+lane (lane < 44)           -> scalar NT store
    const float4* tb4 = reinterpret_cast<const float4*>(tgt_boxes) + (size_t)b * TDIM;
    const int*    lb  = tgt_labels + (size_t)b * TDIM;

    TgtReg A[4];
    #pragma unroll
    for (int i = 0; i < 4; ++i) A[i] = load_tgt(tb4, lb, 4 * lane + i);

    const bool bok = lane < (TDIM - 256);            // lane < 44
    const int  tB  = bok ? (256 + lane) : (TDIM - 1);
    TgtReg Bt = load_tgt(tb4, lb, tB);

    // ---- q loop: wave owns 9 contiguous q's ----
    const int qw = q0 + wave * QPW;
    const float4* pb4 = reinterpret_cast<const float4*>(pred_boxes) + (size_t)b * QDIM + qw;
    float* orow0 = out + ((size_t)b * QDIM + qw) * TDIM;

    #pragma unroll 1
    for (int j = 0; j < QPW; ++j) {
        float4 a = pb4[j];
        const float hw = 0.5f * a.z, hh = 0.5f * a.w;
        const floatx2 ap0  = (floatx2){a.x - hw, a.y - hh};
        const floatx2 ap1  = (floatx2){a.x + hw, a.y + hh};
        const floatx2 awh  = (floatx2){a.z, a.w};
        const floatx2 acc2 = (floatx2){a.x, a.y};
        const float area_a = a.z * a.w;
        const float* cls_j = s_cls + (wave * QPW + j) * CDIM;
        float* po = orow0 + j * TDIM;

        floatx4 res;
        res.x = cost_one(ap0, ap1, awh, acc2, area_a, cls_j, A[0]);
        res.y = cost_one(ap0, ap1, awh, acc2, area_a, cls_j, A[1]);
        res.z = cost_one(ap0, ap1, awh, acc2, area_a, cls_j, A[2]);
        res.w = cost_one(ap0, ap1, awh, acc2, area_a, cls_j, A[3]);
        __builtin_nontemporal_store(res, reinterpret_cast<floatx4*>(po) + lane);

        float cB = cost_one(ap0, ap1, awh, acc2, area_a, cls_j, Bt);
        if (bok)
            __builtin_nontemporal_store(cB, po + 256 + lane);
    }
}

extern "C" void kernel_launch(void* const* d_in, const int* in_sizes, int n_in,
                              void* d_out, int out_size, void* d_ws, size_t ws_size,
                              hipStream_t stream) {
    const float* pred_logits = (const float*)d_in[0];
    const float* pred_boxes  = (const float*)d_in[1];
    const int*   tgt_labels  = (const int*)d_in[2];
    const float* tgt_boxes   = (const float*)d_in[3];
    float* out = (float*)d_out;

    const int B = in_sizes[0] / (QDIM * CDIM);   // 256
    dim3 grid(B * NQB);                          // 256 * 25 = 6400
    dim3 block(256);
    matcher_cost_kernel<<<grid, block, 0, stream>>>(pred_logits, pred_boxes,
                                                    tgt_labels, tgt_boxes, out);
}